// Round 4
// baseline (405.241 us; speedup 1.0000x reference)
//
#include <hip/hip_runtime.h>
#include <hip/hip_bf16.h>
#include <stdint.h>

// KipfMLPGNN: B=32, N=64 nodes, D=128, H=256, L=3 layers.
// Factorizations:
//  - First MLP layer split into per-node sender/receiver halves (k_T, fp16).
//  - Arc blend separates: agg = Sum_c (1-a)*m0 + Sum_c a*m1 -> phase waves.
// k_edge v4: block=(b, 8 r's), 8 waves = phase x d-half x r-half. Ts/Tr in
// LDS (pad-528 rows: conflict-free, no swizzle math), W2 frags hoisted in
// registers (128 VGPR), h built in regs via v_pk f16 ops. ~230 VGPR, no spill.

#define NB 32
#define NN 64
#define DD 128
#define HH 256

typedef __attribute__((ext_vector_type(4))) float f32x4;
typedef __attribute__((ext_vector_type(4))) uint32_t u32x4;
typedef __attribute__((ext_vector_type(8))) _Float16 f16x8;

__device__ __forceinline__ uint64_t cvt4h(f32x4 v) {
  union { _Float16 h[4]; uint64_t u; } x;
  x.h[0] = (_Float16)v[0]; x.h[1] = (_Float16)v[1];
  x.h[2] = (_Float16)v[2]; x.h[3] = (_Float16)v[3];
  return x.u;
}

// E[node][d] = table[x[node]][d]  (2048 x 128 f32)
__global__ __launch_bounds__(256) void k_gather(const int* __restrict__ x,
                                                const float* __restrict__ table,
                                                float* __restrict__ E) {
  int i = blockIdx.x * 256 + threadIdx.x;
  int node = i >> 5;
  ((f32x4*)E)[i] = ((const f32x4*)table)[(size_t)x[node] * 32 + (i & 31)];
}

// W1fp[2][256h][256in] fp16 (natural layout), W2fp[2][128d][256h] fp16.
__global__ __launch_bounds__(256) void k_prep(const float* __restrict__ W1_0,
                                              const float* __restrict__ W1_1,
                                              const float* __restrict__ W2_0,
                                              const float* __restrict__ W2_1,
                                              _Float16* __restrict__ W1fp,
                                              _Float16* __restrict__ W2fp) {
  int tid = blockIdx.x * 256 + threadIdx.x;   // 192*256 = 49152 f32x4 chunks
  const float* src; uint64_t* dst; int off;
  if (tid < 32768) {
    src = (tid < 16384) ? W1_0 : W1_1;
    off = tid & 16383;
    dst = (uint64_t*)W1fp + (tid >> 14) * 16384 + off;
  } else {
    int t2 = tid - 32768;
    src = (t2 < 8192) ? W2_0 : W2_1;
    off = t2 & 8191;
    dst = (uint64_t*)W2fp + (t2 >> 13) * 8192 + off;
  }
  *dst = cvt4h(((const f32x4*)src)[off]);
}

// Tfp[node][1024] = [Ts0 | Tr0+b1_0 | Ts1 | Tr1+b1_1]  (fp16)
// grid (8, 32): x = q*2+half (q in {Ts0,Tr0,Ts1,Tr1}, 128 h-cols), y = 64-node blk
__global__ __launch_bounds__(256) void k_T(const float* __restrict__ E,
                                           const _Float16* __restrict__ W1fp,
                                           const float* __restrict__ b1_0,
                                           const float* __restrict__ b1_1,
                                           _Float16* __restrict__ Tfp) {
  __shared__ char Els[64 * 256];     // 64 nodes x 128 f16, swizzled rows (256B)
  int t = threadIdx.x;
  int gi = blockIdx.x;
  int q = gi >> 1;                   // group 0..3
  int hb = (gi & 1) * 128;           // h-half
  int inoff = (q & 1) * 128;         // sender(0) / receiver(128) input half
  int node0 = blockIdx.y * 64;

  // stage E tile -> fp16 LDS, XOR swizzle ((row&7)<<4)
#pragma unroll
  for (int ii = 0; ii < 8; ++ii) {
    int idx = ii * 256 + t;          // f32x4 chunk: row=idx>>5, ck=idx&31
    int row = idx >> 5, ck = idx & 31;
    f32x4 v = ((const f32x4*)(E + (size_t)node0 * 128))[idx];
    *(uint64_t*)(Els + row * 256 + ((ck * 8) ^ ((row & 7) << 4))) = cvt4h(v);
  }
  __syncthreads();

  int lane = t & 63, w = t >> 6;     // 4 waves, each 64M x 32N
  int col = lane & 15, khi = lane >> 4;

  // hoist B fragments: W1fp[q>>1][hb+n][inoff + k]
  const _Float16* Wq = W1fp + (q >> 1) * 65536;
  f16x8 bfr[2][4];
#pragma unroll
  for (int nt = 0; nt < 2; ++nt) {
    int n = w * 32 + nt * 16 + col;
#pragma unroll
    for (int ks = 0; ks < 4; ++ks)
      bfr[nt][ks] = *(const f16x8*)(Wq + (hb + n) * 256 + inoff + ks * 32 + khi * 8);
  }

  f32x4 acc[4][2];
  const f32x4 z = {0.f, 0.f, 0.f, 0.f};
#pragma unroll
  for (int mt = 0; mt < 4; ++mt)
#pragma unroll
    for (int nt = 0; nt < 2; ++nt) acc[mt][nt] = z;

#pragma unroll
  for (int ks = 0; ks < 4; ++ks) {
    f16x8 a[4];
#pragma unroll
    for (int mt = 0; mt < 4; ++mt) {
      int c = mt * 16 + col;
      a[mt] = *(const f16x8*)(Els + c * 256 + ((ks * 64 + khi * 16) ^ ((c & 7) << 4)));
    }
#pragma unroll
    for (int mt = 0; mt < 4; ++mt)
#pragma unroll
      for (int nt = 0; nt < 2; ++nt)
        acc[mt][nt] = __builtin_amdgcn_mfma_f32_16x16x32_f16(a[mt], bfr[nt][ks],
                                                             acc[mt][nt], 0, 0, 0);
  }

  const float* b1q = (q >> 1) ? b1_1 : b1_0;
  float bv[2];
#pragma unroll
  for (int nt = 0; nt < 2; ++nt)
    bv[nt] = (q & 1) ? b1q[hb + w * 32 + nt * 16 + col] : 0.f;

#pragma unroll
  for (int mt = 0; mt < 4; ++mt)
#pragma unroll
    for (int nt = 0; nt < 2; ++nt)
#pragma unroll
      for (int j = 0; j < 4; ++j) {
        int node = node0 + mt * 16 + khi * 4 + j;
        int cgl = q * 256 + hb + w * 32 + nt * 16 + col;
        Tfp[(size_t)node * 1024 + cgl] = (_Float16)(acc[mt][nt][j] + bv[nt]);
      }
}

// k_edge v4: block = (b, 8 r's), 512 threads / 8 waves.
// wave w: pg=w>>2 (phase), dg=(w>>1)&1 (d-half, 64 cols), rg=w&1 (4 r's).
// LDS: Tsl[2][64] rows pad-528 (67584 B) + Trl[2][8] rows 512 B (8192 B)
//    + Sp[2][8][128] f32 (8192 B) = 83968 B -> 1 block/CU (grid = 256).
__global__ __launch_bounds__(512) void k_edge(const _Float16* __restrict__ Tfp,
                                              const int* __restrict__ arcs,
                                              const float* __restrict__ E,
                                              float* __restrict__ out,
                                              const _Float16* __restrict__ W2fp,
                                              const float* __restrict__ b2_0,
                                              const float* __restrict__ b2_1,
                                              int last) {
  __shared__ char lds[83968];
  char* Tsl = lds;                       // rows (p*64+c), stride 528 B
  char* Trl = lds + 67584;               // rows (p*8+r), stride 512 B
  float* Sp = (float*)(lds + 75776);     // [2][8][128] f32

  int t = threadIdx.x;
  int b = blockIdx.y;
  int rbase = blockIdx.x * 8;
  const _Float16* Tb = Tfp + (size_t)b * NN * 1024;

  // ---- stage Tsl: 4096 chunks of 16 B ----
#pragma unroll
  for (int it = 0; it < 8; ++it) {
    int chunk = it * 512 + t;
    int p = chunk >> 11, c = (chunk >> 5) & 63, kc = chunk & 31;
    *(f16x8*)(Tsl + (p * 64 + c) * 528 + kc * 16) =
        *(const f16x8*)(Tb + c * 1024 + p * 512 + kc * 8);
  }
  // ---- stage Trl: 512 chunks ----
  {
    int p = t >> 8, rr = (t >> 5) & 7, kc = t & 31;
    *(f16x8*)(Trl + (p * 8 + rr) * 512 + kc * 16) =
        *(const f16x8*)(Tb + (rbase + rr) * 1024 + p * 512 + 256 + kc * 8);
  }

  int lane = t & 63, w = t >> 6;
  int col = lane & 15, khi = lane >> 4;
  int pg = w >> 2, dg = (w >> 1) & 1, rg = w & 1;

  // hoist W2 fragments from global (L2-resident): 128 VGPR
  const _Float16* W2p = W2fp + pg * 32768;
  f16x8 bv[4][8];
#pragma unroll
  for (int nt = 0; nt < 4; ++nt) {
    int d = dg * 64 + nt * 16 + col;
#pragma unroll
    for (int ks = 0; ks < 8; ++ks)
      bv[nt][ks] = *(const f16x8*)(W2p + d * 256 + ks * 32 + khi * 8);
  }
  const float* b2p = pg ? b2_1 : b2_0;
  float b2v[4];
#pragma unroll
  for (int nt = 0; nt < 4; ++nt) b2v[nt] = b2p[dg * 64 + nt * 16 + col];

  __syncthreads();

  float Sreg[4][4];
#pragma unroll
  for (int rr = 0; rr < 4; ++rr)
#pragma unroll
    for (int nt = 0; nt < 4; ++nt) Sreg[rr][nt] = 0.f;

  const char* tsbase = Tsl + (pg * 64 + col) * 528 + khi * 16;
  const char* trbase = Trl + (pg * 8 + rg * 4) * 512 + khi * 16;

#pragma unroll
  for (int mt = 0; mt < 4; ++mt) {
    f16x8 ts[8];
#pragma unroll
    for (int ks = 0; ks < 8; ++ks)
      ts[ks] = *(const f16x8*)(tsbase + mt * (16 * 528) + ks * 64);

#pragma unroll
    for (int rr = 0; rr < 4; ++rr) {
      int r = rbase + rg * 4 + rr;
      f32x4 acc[4];
      const f32x4 z = {0.f, 0.f, 0.f, 0.f};
#pragma unroll
      for (int nt = 0; nt < 4; ++nt) acc[nt] = z;

#pragma unroll
      for (int ks = 0; ks < 8; ++ks) {
        f16x8 tr = *(const f16x8*)(trbase + rr * 512 + ks * 64);
        f16x8 zv = {};
        f16x8 a = __builtin_elementwise_max(ts[ks] + tr, zv);
#pragma unroll
        for (int nt = 0; nt < 4; ++nt)
          acc[nt] = __builtin_amdgcn_mfma_f32_16x16x32_f16(a, bv[nt][ks],
                                                           acc[nt], 0, 0, 0);
      }

      const int4 ai = *(const int4*)(arcs + ((size_t)(b * 64 + r)) * 64 +
                                     mt * 16 + khi * 4);
#pragma unroll
      for (int j = 0; j < 4; ++j) {
        int av = (j == 0) ? ai.x : (j == 1) ? ai.y : (j == 2) ? ai.z : ai.w;
        float wgt = pg ? (float)av : 1.0f - (float)av;
#pragma unroll
        for (int nt = 0; nt < 4; ++nt) {
          float m = fmaxf(acc[nt][j] + b2v[nt], 0.f);
          Sreg[rr][nt] = fmaf(wgt, m, Sreg[rr][nt]);
        }
      }
    }
  }

  // reduce over khi groups, write per-phase partial to Sp
#pragma unroll
  for (int rr = 0; rr < 4; ++rr)
#pragma unroll
    for (int nt = 0; nt < 4; ++nt) {
      float v = Sreg[rr][nt];
      v += __shfl_xor(v, 16);
      v += __shfl_xor(v, 32);
      if (khi == 0)
        Sp[(pg * 8 + rg * 4 + rr) * 128 + dg * 64 + nt * 16 + col] = v;
    }
  __syncthreads();

  if (last) {
    if (t < 128)
      out[b * DD + t] = E[(size_t)b * NN * DD + t] + Sp[t] + Sp[1024 + t];
  } else {
#pragma unroll
    for (int s = t; s < 1024; s += 512) {
      int r = s >> 7, d = s & 127;
      size_t row = (size_t)b * NN + rbase + r;
      out[row * DD + d] = E[row * DD + d] + Sp[s] + Sp[1024 + s];
    }
  }
}

extern "C" void kernel_launch(void* const* d_in, const int* in_sizes, int n_in,
                              void* d_out, int out_size, void* d_ws, size_t ws_size,
                              hipStream_t stream) {
  const int* x       = (const int*)d_in[0];
  const int* arcs    = (const int*)d_in[1];
  const float* table = (const float*)d_in[3];
  const float* W1_0  = (const float*)d_in[4];
  const float* b1_0  = (const float*)d_in[5];
  const float* W2_0  = (const float*)d_in[6];
  const float* b2_0  = (const float*)d_in[7];
  const float* W1_1  = (const float*)d_in[8];
  const float* b1_1  = (const float*)d_in[9];
  const float* W2_1  = (const float*)d_in[10];
  const float* b2_1  = (const float*)d_in[11];
  float* out = (float*)d_out;

  char* ws = (char*)d_ws;
  float* E         = (float*)ws;                      // 1 MB
  _Float16* Tfp    = (_Float16*)(ws + (1u << 20));    // 4 MB
  _Float16* W1fp   = (_Float16*)(ws + (5u << 20));    // 256 KB
  _Float16* W2fp   = (_Float16*)(ws + (5u << 20) + (256u << 10));  // 128 KB

  k_gather<<<256, 256, 0, stream>>>(x, table, E);
  k_prep<<<192, 256, 0, stream>>>(W1_0, W1_1, W2_0, W2_1, W1fp, W2fp);
  for (int l = 0; l < 3; ++l) {
    int last = (l == 2);
    k_T<<<dim3(8, 32), 256, 0, stream>>>(E, W1fp, b1_0, b1_1, Tfp);
    k_edge<<<dim3(last ? 1 : 8, 32), 512, 0, stream>>>(
        Tfp, arcs, E, last ? out : E, W2fp, b2_0, b2_1, last);
  }
}

// Round 5
// 404.868 us; speedup vs baseline: 1.0009x; 1.0009x over previous
//
#include <hip/hip_runtime.h>
#include <hip/hip_bf16.h>
#include <stdint.h>

// KipfMLPGNN: B=32, N=64 nodes, D=128, H=256, L=3 layers.
// Factorizations:
//  - First MLP layer split into per-node sender/receiver halves (k_T, fp16).
//  - Arc blend separates: agg = Sum_c (1-a)*m0 + Sum_c a*m1 -> phase waves.
// k_edge v5 = v4 + amdgpu_waves_per_eu(2,2): LDS already caps occupancy at
// 2 waves/EU; pinning it raises the RA's VGPR budget 128->256 so the ~230
// live VGPRs (bv hoist 128 + ts 32 + acc/Sreg) stop spilling to scratch.

#define NB 32
#define NN 64
#define DD 128
#define HH 256

typedef __attribute__((ext_vector_type(4))) float f32x4;
typedef __attribute__((ext_vector_type(4))) uint32_t u32x4;
typedef __attribute__((ext_vector_type(8))) _Float16 f16x8;

__device__ __forceinline__ uint64_t cvt4h(f32x4 v) {
  union { _Float16 h[4]; uint64_t u; } x;
  x.h[0] = (_Float16)v[0]; x.h[1] = (_Float16)v[1];
  x.h[2] = (_Float16)v[2]; x.h[3] = (_Float16)v[3];
  return x.u;
}

// E[node][d] = table[x[node]][d]  (2048 x 128 f32)
__global__ __launch_bounds__(256) void k_gather(const int* __restrict__ x,
                                                const float* __restrict__ table,
                                                float* __restrict__ E) {
  int i = blockIdx.x * 256 + threadIdx.x;
  int node = i >> 5;
  ((f32x4*)E)[i] = ((const f32x4*)table)[(size_t)x[node] * 32 + (i & 31)];
}

// W1fp[2][256h][256in] fp16 (natural layout), W2fp[2][128d][256h] fp16.
__global__ __launch_bounds__(256) void k_prep(const float* __restrict__ W1_0,
                                              const float* __restrict__ W1_1,
                                              const float* __restrict__ W2_0,
                                              const float* __restrict__ W2_1,
                                              _Float16* __restrict__ W1fp,
                                              _Float16* __restrict__ W2fp) {
  int tid = blockIdx.x * 256 + threadIdx.x;   // 192*256 = 49152 f32x4 chunks
  const float* src; uint64_t* dst; int off;
  if (tid < 32768) {
    src = (tid < 16384) ? W1_0 : W1_1;
    off = tid & 16383;
    dst = (uint64_t*)W1fp + (tid >> 14) * 16384 + off;
  } else {
    int t2 = tid - 32768;
    src = (t2 < 8192) ? W2_0 : W2_1;
    off = t2 & 8191;
    dst = (uint64_t*)W2fp + (t2 >> 13) * 8192 + off;
  }
  *dst = cvt4h(((const f32x4*)src)[off]);
}

// Tfp[node][1024] = [Ts0 | Tr0+b1_0 | Ts1 | Tr1+b1_1]  (fp16)
// grid (8, 32): x = q*2+half (q in {Ts0,Tr0,Ts1,Tr1}, 128 h-cols), y = 64-node blk
__global__ __launch_bounds__(256) void k_T(const float* __restrict__ E,
                                           const _Float16* __restrict__ W1fp,
                                           const float* __restrict__ b1_0,
                                           const float* __restrict__ b1_1,
                                           _Float16* __restrict__ Tfp) {
  __shared__ char Els[64 * 256];     // 64 nodes x 128 f16, swizzled rows (256B)
  int t = threadIdx.x;
  int gi = blockIdx.x;
  int q = gi >> 1;                   // group 0..3
  int hb = (gi & 1) * 128;           // h-half
  int inoff = (q & 1) * 128;         // sender(0) / receiver(128) input half
  int node0 = blockIdx.y * 64;

  // stage E tile -> fp16 LDS, XOR swizzle ((row&7)<<4)
#pragma unroll
  for (int ii = 0; ii < 8; ++ii) {
    int idx = ii * 256 + t;          // f32x4 chunk: row=idx>>5, ck=idx&31
    int row = idx >> 5, ck = idx & 31;
    f32x4 v = ((const f32x4*)(E + (size_t)node0 * 128))[idx];
    *(uint64_t*)(Els + row * 256 + ((ck * 8) ^ ((row & 7) << 4))) = cvt4h(v);
  }
  __syncthreads();

  int lane = t & 63, w = t >> 6;     // 4 waves, each 64M x 32N
  int col = lane & 15, khi = lane >> 4;

  // hoist B fragments: W1fp[q>>1][hb+n][inoff + k]
  const _Float16* Wq = W1fp + (q >> 1) * 65536;
  f16x8 bfr[2][4];
#pragma unroll
  for (int nt = 0; nt < 2; ++nt) {
    int n = w * 32 + nt * 16 + col;
#pragma unroll
    for (int ks = 0; ks < 4; ++ks)
      bfr[nt][ks] = *(const f16x8*)(Wq + (hb + n) * 256 + inoff + ks * 32 + khi * 8);
  }

  f32x4 acc[4][2];
  const f32x4 z = {0.f, 0.f, 0.f, 0.f};
#pragma unroll
  for (int mt = 0; mt < 4; ++mt)
#pragma unroll
    for (int nt = 0; nt < 2; ++nt) acc[mt][nt] = z;

#pragma unroll
  for (int ks = 0; ks < 4; ++ks) {
    f16x8 a[4];
#pragma unroll
    for (int mt = 0; mt < 4; ++mt) {
      int c = mt * 16 + col;
      a[mt] = *(const f16x8*)(Els + c * 256 + ((ks * 64 + khi * 16) ^ ((c & 7) << 4)));
    }
#pragma unroll
    for (int mt = 0; mt < 4; ++mt)
#pragma unroll
      for (int nt = 0; nt < 2; ++nt)
        acc[mt][nt] = __builtin_amdgcn_mfma_f32_16x16x32_f16(a[mt], bfr[nt][ks],
                                                             acc[mt][nt], 0, 0, 0);
  }

  const float* b1q = (q >> 1) ? b1_1 : b1_0;
  float bv[2];
#pragma unroll
  for (int nt = 0; nt < 2; ++nt)
    bv[nt] = (q & 1) ? b1q[hb + w * 32 + nt * 16 + col] : 0.f;

#pragma unroll
  for (int mt = 0; mt < 4; ++mt)
#pragma unroll
    for (int nt = 0; nt < 2; ++nt)
#pragma unroll
      for (int j = 0; j < 4; ++j) {
        int node = node0 + mt * 16 + khi * 4 + j;
        int cgl = q * 256 + hb + w * 32 + nt * 16 + col;
        Tfp[(size_t)node * 1024 + cgl] = (_Float16)(acc[mt][nt][j] + bv[nt]);
      }
}

// k_edge v5: block = (b, 8 r's), 512 threads / 8 waves, 2 waves/EU pinned.
// wave w: pg=w>>2 (phase), dg=(w>>1)&1 (d-half, 64 cols), rg=w&1 (4 r's).
// LDS: Tsl[2][64] rows pad-528 (67584 B) + Trl[2][8] rows 512 B (8192 B)
//    + Sp[2][8][128] f32 (8192 B) = 83968 B -> 1 block/CU (grid = 256).
__global__ __launch_bounds__(512)
__attribute__((amdgpu_waves_per_eu(2, 2)))
void k_edge(const _Float16* __restrict__ Tfp,
            const int* __restrict__ arcs,
            const float* __restrict__ E,
            float* __restrict__ out,
            const _Float16* __restrict__ W2fp,
            const float* __restrict__ b2_0,
            const float* __restrict__ b2_1,
            int last) {
  __shared__ char lds[83968];
  char* Tsl = lds;                       // rows (p*64+c), stride 528 B
  char* Trl = lds + 67584;               // rows (p*8+r), stride 512 B
  float* Sp = (float*)(lds + 75776);     // [2][8][128] f32

  int t = threadIdx.x;
  int b = blockIdx.y;
  int rbase = blockIdx.x * 8;
  const _Float16* Tb = Tfp + (size_t)b * NN * 1024;

  // ---- stage Tsl: 4096 chunks of 16 B ----
#pragma unroll
  for (int it = 0; it < 8; ++it) {
    int chunk = it * 512 + t;
    int p = chunk >> 11, c = (chunk >> 5) & 63, kc = chunk & 31;
    *(f16x8*)(Tsl + (p * 64 + c) * 528 + kc * 16) =
        *(const f16x8*)(Tb + c * 1024 + p * 512 + kc * 8);
  }
  // ---- stage Trl: 512 chunks ----
  {
    int p = t >> 8, rr = (t >> 5) & 7, kc = t & 31;
    *(f16x8*)(Trl + (p * 8 + rr) * 512 + kc * 16) =
        *(const f16x8*)(Tb + (rbase + rr) * 1024 + p * 512 + 256 + kc * 8);
  }

  int lane = t & 63, w = t >> 6;
  int col = lane & 15, khi = lane >> 4;
  int pg = w >> 2, dg = (w >> 1) & 1, rg = w & 1;

  // hoist W2 fragments from global (L2-resident): 128 VGPR
  const _Float16* W2p = W2fp + pg * 32768;
  f16x8 bv[4][8];
#pragma unroll
  for (int nt = 0; nt < 4; ++nt) {
    int d = dg * 64 + nt * 16 + col;
#pragma unroll
    for (int ks = 0; ks < 8; ++ks)
      bv[nt][ks] = *(const f16x8*)(W2p + d * 256 + ks * 32 + khi * 8);
  }
  const float* b2p = pg ? b2_1 : b2_0;
  float b2v[4];
#pragma unroll
  for (int nt = 0; nt < 4; ++nt) b2v[nt] = b2p[dg * 64 + nt * 16 + col];

  __syncthreads();

  float Sreg[4][4];
#pragma unroll
  for (int rr = 0; rr < 4; ++rr)
#pragma unroll
    for (int nt = 0; nt < 4; ++nt) Sreg[rr][nt] = 0.f;

  const char* tsbase = Tsl + (pg * 64 + col) * 528 + khi * 16;
  const char* trbase = Trl + (pg * 8 + rg * 4) * 512 + khi * 16;

#pragma unroll
  for (int mt = 0; mt < 4; ++mt) {
    f16x8 ts[8];
#pragma unroll
    for (int ks = 0; ks < 8; ++ks)
      ts[ks] = *(const f16x8*)(tsbase + mt * (16 * 528) + ks * 64);

#pragma unroll
    for (int rr = 0; rr < 4; ++rr) {
      int r = rbase + rg * 4 + rr;
      f32x4 acc[4];
      const f32x4 z = {0.f, 0.f, 0.f, 0.f};
#pragma unroll
      for (int nt = 0; nt < 4; ++nt) acc[nt] = z;

#pragma unroll
      for (int ks = 0; ks < 8; ++ks) {
        f16x8 tr = *(const f16x8*)(trbase + rr * 512 + ks * 64);
        f16x8 zv = {};
        f16x8 a = __builtin_elementwise_max(ts[ks] + tr, zv);
#pragma unroll
        for (int nt = 0; nt < 4; ++nt)
          acc[nt] = __builtin_amdgcn_mfma_f32_16x16x32_f16(a, bv[nt][ks],
                                                           acc[nt], 0, 0, 0);
      }

      const int4 ai = *(const int4*)(arcs + ((size_t)(b * 64 + r)) * 64 +
                                     mt * 16 + khi * 4);
#pragma unroll
      for (int j = 0; j < 4; ++j) {
        int av = (j == 0) ? ai.x : (j == 1) ? ai.y : (j == 2) ? ai.z : ai.w;
        float wgt = pg ? (float)av : 1.0f - (float)av;
#pragma unroll
        for (int nt = 0; nt < 4; ++nt) {
          float m = fmaxf(acc[nt][j] + b2v[nt], 0.f);
          Sreg[rr][nt] = fmaf(wgt, m, Sreg[rr][nt]);
        }
      }
    }
  }

  // reduce over khi groups, write per-phase partial to Sp
#pragma unroll
  for (int rr = 0; rr < 4; ++rr)
#pragma unroll
    for (int nt = 0; nt < 4; ++nt) {
      float v = Sreg[rr][nt];
      v += __shfl_xor(v, 16);
      v += __shfl_xor(v, 32);
      if (khi == 0)
        Sp[(pg * 8 + rg * 4 + rr) * 128 + dg * 64 + nt * 16 + col] = v;
    }
  __syncthreads();

  if (last) {
    if (t < 128)
      out[b * DD + t] = E[(size_t)b * NN * DD + t] + Sp[t] + Sp[1024 + t];
  } else {
#pragma unroll
    for (int s = t; s < 1024; s += 512) {
      int r = s >> 7, d = s & 127;
      size_t row = (size_t)b * NN + rbase + r;
      out[row * DD + d] = E[row * DD + d] + Sp[s] + Sp[1024 + s];
    }
  }
}

extern "C" void kernel_launch(void* const* d_in, const int* in_sizes, int n_in,
                              void* d_out, int out_size, void* d_ws, size_t ws_size,
                              hipStream_t stream) {
  const int* x       = (const int*)d_in[0];
  const int* arcs    = (const int*)d_in[1];
  const float* table = (const float*)d_in[3];
  const float* W1_0  = (const float*)d_in[4];
  const float* b1_0  = (const float*)d_in[5];
  const float* W2_0  = (const float*)d_in[6];
  const float* b2_0  = (const float*)d_in[7];
  const float* W1_1  = (const float*)d_in[8];
  const float* b1_1  = (const float*)d_in[9];
  const float* W2_1  = (const float*)d_in[10];
  const float* b2_1  = (const float*)d_in[11];
  float* out = (float*)d_out;

  char* ws = (char*)d_ws;
  float* E         = (float*)ws;                      // 1 MB
  _Float16* Tfp    = (_Float16*)(ws + (1u << 20));    // 4 MB
  _Float16* W1fp   = (_Float16*)(ws + (5u << 20));    // 256 KB
  _Float16* W2fp   = (_Float16*)(ws + (5u << 20) + (256u << 10));  // 128 KB

  k_gather<<<256, 256, 0, stream>>>(x, table, E);
  k_prep<<<192, 256, 0, stream>>>(W1_0, W1_1, W2_0, W2_1, W1fp, W2fp);
  for (int l = 0; l < 3; ++l) {
    int last = (l == 2);
    k_T<<<dim3(8, 32), 256, 0, stream>>>(E, W1fp, b1_0, b1_1, Tfp);
    k_edge<<<dim3(last ? 1 : 8, 32), 512, 0, stream>>>(
        Tfp, arcs, E, last ? out : E, W2fp, b2_0, b2_1, last);
  }
}

// Round 7
// 128.833 us; speedup vs baseline: 3.1455x; 3.1426x over previous
//
#include <hip/hip_runtime.h>
#include <hip/hip_bf16.h>
#include <stdint.h>

// KipfMLPGNN: B=32, N=64 nodes, D=128, H=256, L=3 layers.
// Factorizations:
//  - First MLP layer split into per-node sender/receiver halves (k_T, fp16).
//  - Arc blend separates: agg = Sum_c (1-a)*m0 + Sum_c a*m1 -> phase = grid.z,
//    combined across blocks with f32 atomicAdd (threshold 55.68 >> LSB noise).
// k_edge v7: sized for the 128-VGPR budget the allocator enforces (R3-R6):
// wave owns 16 d-cols -> bv hoist 32 regs; ts via swizzled LDS (32 regs/mt);
// tr streamed from global (L1-broadcast, VMEM pipe). ~115 live VGPR, no spill.

#define NB 32
#define NN 64
#define DD 128
#define HH 256

typedef __attribute__((ext_vector_type(4))) float f32x4;
typedef __attribute__((ext_vector_type(8))) _Float16 f16x8;

__device__ __forceinline__ uint64_t cvt4h(f32x4 v) {
  union { _Float16 h[4]; uint64_t u; } x;
  x.h[0] = (_Float16)v[0]; x.h[1] = (_Float16)v[1];
  x.h[2] = (_Float16)v[2]; x.h[3] = (_Float16)v[3];
  return x.u;
}

// E[node][d] = table[x[node]][d]  (2048 x 128 f32)
__global__ __launch_bounds__(256) void k_gather(const int* __restrict__ x,
                                                const float* __restrict__ table,
                                                float* __restrict__ E) {
  int i = blockIdx.x * 256 + threadIdx.x;
  int node = i >> 5;
  ((f32x4*)E)[i] = ((const f32x4*)table)[(size_t)x[node] * 32 + (i & 31)];
}

// W1fp[2][256h][256in] fp16 (natural layout), W2fp[2][128d][256h] fp16.
__global__ __launch_bounds__(256) void k_prep(const float* __restrict__ W1_0,
                                              const float* __restrict__ W1_1,
                                              const float* __restrict__ W2_0,
                                              const float* __restrict__ W2_1,
                                              _Float16* __restrict__ W1fp,
                                              _Float16* __restrict__ W2fp) {
  int tid = blockIdx.x * 256 + threadIdx.x;   // 192*256 = 49152 f32x4 chunks
  const float* src; uint64_t* dst; int off;
  if (tid < 32768) {
    src = (tid < 16384) ? W1_0 : W1_1;
    off = tid & 16383;
    dst = (uint64_t*)W1fp + (tid >> 14) * 16384 + off;
  } else {
    int t2 = tid - 32768;
    src = (t2 < 8192) ? W2_0 : W2_1;
    off = t2 & 8191;
    dst = (uint64_t*)W2fp + (t2 >> 13) * 8192 + off;
  }
  *dst = cvt4h(((const f32x4*)src)[off]);
}

// Tfp[node][1024] = [Ts0 | Tr0+b1_0 | Ts1 | Tr1+b1_1]  (fp16)
// grid (8, 32): x = q*2+half (q in {Ts0,Tr0,Ts1,Tr1}, 128 h-cols), y = 64-node blk
__global__ __launch_bounds__(256) void k_T(const float* __restrict__ E,
                                           const _Float16* __restrict__ W1fp,
                                           const float* __restrict__ b1_0,
                                           const float* __restrict__ b1_1,
                                           _Float16* __restrict__ Tfp) {
  __shared__ char Els[64 * 256];     // 64 nodes x 128 f16, swizzled rows (256B)
  int t = threadIdx.x;
  int gi = blockIdx.x;
  int q = gi >> 1;                   // group 0..3
  int hb = (gi & 1) * 128;           // h-half
  int inoff = (q & 1) * 128;         // sender(0) / receiver(128) input half
  int node0 = blockIdx.y * 64;

  // stage E tile -> fp16 LDS, XOR swizzle ((row&7)<<4)
#pragma unroll
  for (int ii = 0; ii < 8; ++ii) {
    int idx = ii * 256 + t;          // f32x4 chunk: row=idx>>5, ck=idx&31
    int row = idx >> 5, ck = idx & 31;
    f32x4 v = ((const f32x4*)(E + (size_t)node0 * 128))[idx];
    *(uint64_t*)(Els + row * 256 + ((ck * 8) ^ ((row & 7) << 4))) = cvt4h(v);
  }
  __syncthreads();

  int lane = t & 63, w = t >> 6;     // 4 waves, each 64M x 32N
  int col = lane & 15, khi = lane >> 4;

  // hoist B fragments: W1fp[q>>1][hb+n][inoff + k]
  const _Float16* Wq = W1fp + (q >> 1) * 65536;
  f16x8 bfr[2][4];
#pragma unroll
  for (int nt = 0; nt < 2; ++nt) {
    int n = w * 32 + nt * 16 + col;
#pragma unroll
    for (int ks = 0; ks < 4; ++ks)
      bfr[nt][ks] = *(const f16x8*)(Wq + (hb + n) * 256 + inoff + ks * 32 + khi * 8);
  }

  f32x4 acc[4][2];
  const f32x4 z = {0.f, 0.f, 0.f, 0.f};
#pragma unroll
  for (int mt = 0; mt < 4; ++mt)
#pragma unroll
    for (int nt = 0; nt < 2; ++nt) acc[mt][nt] = z;

#pragma unroll
  for (int ks = 0; ks < 4; ++ks) {
    f16x8 a[4];
#pragma unroll
    for (int mt = 0; mt < 4; ++mt) {
      int c = mt * 16 + col;
      a[mt] = *(const f16x8*)(Els + c * 256 + ((ks * 64 + khi * 16) ^ ((c & 7) << 4)));
    }
#pragma unroll
    for (int mt = 0; mt < 4; ++mt)
#pragma unroll
      for (int nt = 0; nt < 2; ++nt)
        acc[mt][nt] = __builtin_amdgcn_mfma_f32_16x16x32_f16(a[mt], bfr[nt][ks],
                                                             acc[mt][nt], 0, 0, 0);
  }

  const float* b1q = (q >> 1) ? b1_1 : b1_0;
  float bv[2];
#pragma unroll
  for (int nt = 0; nt < 2; ++nt)
    bv[nt] = (q & 1) ? b1q[hb + w * 32 + nt * 16 + col] : 0.f;

#pragma unroll
  for (int mt = 0; mt < 4; ++mt)
#pragma unroll
    for (int nt = 0; nt < 2; ++nt)
#pragma unroll
      for (int j = 0; j < 4; ++j) {
        int node = node0 + mt * 16 + khi * 4 + j;
        int cgl = q * 256 + hb + w * 32 + nt * 16 + col;
        Tfp[(size_t)node * 1024 + cgl] = (_Float16)(acc[mt][nt][j] + bv[nt]);
      }
}

// out[b][d] = E[b][0][d]  (initializes d_out deterministically each call)
__global__ __launch_bounds__(256) void k_init(const float* __restrict__ E,
                                              float* __restrict__ out) {
  int i = blockIdx.x * 256 + threadIdx.x;      // 4096
  out[i] = E[(size_t)(i >> 7) * (NN * DD) + (i & 127)];
}

// k_edge v7: grid (nrb*2, 32, 2) — x: r-block(8 rows) x d-half, y: batch,
// z: phase. Block 256 thr / 4 waves; wave owns 16 d-cols.
// Per wave: bv[8] (W2 cols, 32 regs) + per-mt ts[8] from swizzled LDS
// (32 regs) + per-r tr[8] streamed from global (32 regs, L1 broadcast).
// Epilogue: blend by arc weight, c-sum via shfl, atomicAdd to Eout.
template <int LAST>
__global__ __launch_bounds__(256) void k_edge(const _Float16* __restrict__ Tfp,
                                              const int* __restrict__ arcs,
                                              float* __restrict__ Eout,
                                              const _Float16* __restrict__ W2fp,
                                              const float* __restrict__ b2_0,
                                              const float* __restrict__ b2_1) {
  constexpr int NR = LAST ? 1 : 8;
  __shared__ char Tsl[64 * 512];     // 64 c-rows x 256 k fp16, XOR swizzled
  int t = threadIdx.x;
  int p = blockIdx.z, b = blockIdx.y;
  int rb = blockIdx.x >> 1, dh = blockIdx.x & 1;
  int rbase = rb * 8;
  const _Float16* Tb = Tfp + (size_t)b * NN * 1024;

  // stage this phase's sender tile: 2048 x 16B chunks
#pragma unroll
  for (int it = 0; it < 8; ++it) {
    int idx = it * 256 + t, row = idx >> 5, ck = idx & 31;
    *(f16x8*)(Tsl + row * 512 + ((ck * 16) ^ ((row & 7) << 4))) =
        *(const f16x8*)(Tb + row * 1024 + p * 512 + ck * 8);
  }

  int lane = t & 63, w = t >> 6;
  int col = lane & 15, khi = lane >> 4;
  int d = dh * 64 + w * 16 + col;

  // hoist W2 column fragments (32 VGPR)
  const _Float16* W2p = W2fp + p * 32768;
  f16x8 bv[8];
#pragma unroll
  for (int ks = 0; ks < 8; ++ks)
    bv[ks] = *(const f16x8*)(W2p + d * 256 + ks * 32 + khi * 8);
  float b2v = (p ? b2_1 : b2_0)[d];
  __syncthreads();

  float Sreg[NR];
#pragma unroll
  for (int rr = 0; rr < NR; ++rr) Sreg[rr] = 0.f;

#pragma unroll
  for (int mt = 0; mt < 4; ++mt) {
    int c = mt * 16 + col;
    f16x8 ts[8];
#pragma unroll
    for (int ks = 0; ks < 8; ++ks)
      ts[ks] = *(const f16x8*)(Tsl + c * 512 +
                               ((ks * 64 + khi * 16) ^ ((c & 7) << 4)));
#pragma unroll
    for (int rr = 0; rr < NR; ++rr) {
      int r = rbase + rr;
      const _Float16* trp = Tb + r * 1024 + p * 512 + 256 + khi * 8;
      f16x8 tr[8];
#pragma unroll
      for (int ks = 0; ks < 8; ++ks)
        tr[ks] = *(const f16x8*)(trp + ks * 32);

      f32x4 acc = {0.f, 0.f, 0.f, 0.f};
#pragma unroll
      for (int ks = 0; ks < 8; ++ks) {
        f16x8 zv = {};
        f16x8 a = __builtin_elementwise_max(ts[ks] + tr[ks], zv);
        acc = __builtin_amdgcn_mfma_f32_16x16x32_f16(a, bv[ks], acc, 0, 0, 0);
      }

      const int4 ai = *(const int4*)(arcs + ((size_t)(b * NN + r)) * NN +
                                     mt * 16 + khi * 4);
#pragma unroll
      for (int j = 0; j < 4; ++j) {
        int av = (j == 0) ? ai.x : (j == 1) ? ai.y : (j == 2) ? ai.z : ai.w;
        float wgt = p ? (float)av : 1.0f - (float)av;
        Sreg[rr] = fmaf(wgt, fmaxf(acc[j] + b2v, 0.f), Sreg[rr]);
      }
    }
  }

#pragma unroll
  for (int rr = 0; rr < NR; ++rr) {
    float v = Sreg[rr];
    v += __shfl_xor(v, 16);
    v += __shfl_xor(v, 32);
    if (khi == 0) {
      if (LAST)
        atomicAdd(Eout + b * DD + d, v);
      else
        atomicAdd(Eout + ((size_t)(b * NN + rbase + rr)) * DD + d, v);
    }
  }
}

extern "C" void kernel_launch(void* const* d_in, const int* in_sizes, int n_in,
                              void* d_out, int out_size, void* d_ws, size_t ws_size,
                              hipStream_t stream) {
  const int* x       = (const int*)d_in[0];
  const int* arcs    = (const int*)d_in[1];
  const float* table = (const float*)d_in[3];
  const float* W1_0  = (const float*)d_in[4];
  const float* b1_0  = (const float*)d_in[5];
  const float* W2_0  = (const float*)d_in[6];
  const float* b2_0  = (const float*)d_in[7];
  const float* W1_1  = (const float*)d_in[8];
  const float* b1_1  = (const float*)d_in[9];
  const float* W2_1  = (const float*)d_in[10];
  const float* b2_1  = (const float*)d_in[11];
  float* out = (float*)d_out;

  char* ws = (char*)d_ws;
  float* E         = (float*)ws;                      // 1 MB
  _Float16* Tfp    = (_Float16*)(ws + (1u << 20));    // 4 MB
  _Float16* W1fp   = (_Float16*)(ws + (5u << 20));    // 256 KB
  _Float16* W2fp   = (_Float16*)(ws + (5u << 20) + (256u << 10));  // 128 KB

  k_gather<<<256, 256, 0, stream>>>(x, table, E);
  k_prep<<<192, 256, 0, stream>>>(W1_0, W1_1, W2_0, W2_1, W1fp, W2fp);
  for (int l = 0; l < 3; ++l) {
    k_T<<<dim3(8, 32), 256, 0, stream>>>(E, W1fp, b1_0, b1_1, Tfp);
    if (l == 2) {
      k_init<<<16, 256, 0, stream>>>(E, out);
      k_edge<1><<<dim3(2, 32, 2), 256, 0, stream>>>(Tfp, arcs, out,
                                                    W2fp, b2_0, b2_1);
    } else {
      k_edge<0><<<dim3(16, 32, 2), 256, 0, stream>>>(Tfp, arcs, E,
                                                     W2fp, b2_0, b2_1);
    }
  }
}